// Round 5
// baseline (315.604 us; speedup 1.0000x reference)
//
#include <hip/hip_runtime.h>
#include <cstdint>
#include <cstddef>

typedef _Float16 h16;
typedef _Float16 h16x4 __attribute__((ext_vector_type(4)));
typedef _Float16 h16x8 __attribute__((ext_vector_type(8)));
typedef float fx4 __attribute__((ext_vector_type(4)));

static constexpr int B_ = 8, N_ = 4096, E_ = 1024, C_ = 512;
static constexpr float SCALE = 0.044194173824159216f; // 1/sqrt(512)

// async global->LDS, 16B per lane; LDS dest is wave-uniform base + lane*16
__device__ __forceinline__ void glds16(const h16* g, h16* l) {
  __builtin_amdgcn_global_load_lds(
      (const __attribute__((address_space(1))) unsigned int*)g,
      (__attribute__((address_space(3))) unsigned int*)l, 16, 0, 0);
}

// ---------------- fp32 -> f16 convert, 8 elems/thread ----------------
__global__ __launch_bounds__(256) void cvt_kernel(const float* __restrict__ src,
                                                  h16* __restrict__ dst, int n8) {
  int i = blockIdx.x * 256 + threadIdx.x;
  if (i >= n8) return;
  const float4* s4 = (const float4*)src;
  float4 a = s4[2 * i], b = s4[2 * i + 1];
  h16x8 o;
  o[0] = (h16)a.x; o[1] = (h16)a.y; o[2] = (h16)a.z; o[3] = (h16)a.w;
  o[4] = (h16)b.x; o[5] = (h16)b.y; o[6] = (h16)b.z; o[7] = (h16)b.w;
  *(h16x8*)(dst + (size_t)i * 8) = o;
}

// ------- 128x128 gemm_bt: C[m,n] = sum_k A[m,k]*B[n,k], all-f16 glds16 ----
// MODE 0: Q-proj   out f16 = acc + bias[n]
// MODE 1: KV-proj  +bias; K row-major, V -> Vt(B,C,E) packed transposed
// MODE 2: scores   out f16 = exp(acc*SCALE), fp32 atomic row-sums (batched z)
// MODE 3: PV       plain gemm, epilogue *1/rowsum, fp32 out      (batched z)
template <int MODE>
__global__ __launch_bounds__(256) void gemm_bt(
    const h16* __restrict__ Ah, const h16* __restrict__ Bm,
    const float* __restrict__ bias,
    h16* __restrict__ outH, h16* __restrict__ outK, h16* __restrict__ outVt,
    float* __restrict__ outF, float* __restrict__ rowsum,
    int Ncols, int K) {
  __shared__ h16 sA[128 * 32];
  __shared__ h16 sB[128 * 32];
  const int tid = threadIdx.x;
  const int wave = tid >> 6, lane = tid & 63;
  const int wm = wave >> 1, wn = wave & 1;
  const int lr = lane & 15, kq = lane >> 4;
  const int mBase = blockIdx.x * 128, nBase = blockIdx.y * 128;
  const int z = blockIdx.z;
  if (MODE == 2) { Ah += (size_t)z * N_ * C_; Bm += (size_t)z * E_ * C_;
                   outH += (size_t)z * N_ * E_; rowsum += (size_t)z * N_; }
  if (MODE == 3) { Ah += (size_t)z * N_ * E_; Bm += (size_t)z * C_ * E_;
                   outF += (size_t)z * N_ * C_; rowsum += (size_t)z * N_; }

  fx4 acc[4][4];
#pragma unroll
  for (int i = 0; i < 4; i++)
#pragma unroll
    for (int j = 0; j < 4; j++) acc[i][j] = (fx4){0.f, 0.f, 0.f, 0.f};

  const int rowInA = lane >> 2, colInA = (lane & 3) * 8;

  for (int kb = 0; kb < K; kb += 32) {
    __syncthreads();
#pragma unroll
    for (int i = 0; i < 2; i++) {
      int chunk = wave + i * 4;
      glds16(Ah + (size_t)(mBase + chunk * 16 + rowInA) * K + kb + colInA,
             &sA[chunk * 512]);
      glds16(Bm + (size_t)(nBase + chunk * 16 + rowInA) * K + kb + colInA,
             &sB[chunk * 512]);
    }
    __syncthreads();
    h16x8 af[4], bf[4];
#pragma unroll
    for (int mi = 0; mi < 4; mi++)
      af[mi] = *(const h16x8*)&sA[(wm * 64 + mi * 16 + lr) * 32 + kq * 8];
#pragma unroll
    for (int ni = 0; ni < 4; ni++)
      bf[ni] = *(const h16x8*)&sB[(wn * 64 + ni * 16 + lr) * 32 + kq * 8];
#pragma unroll
    for (int mi = 0; mi < 4; mi++)
#pragma unroll
      for (int ni = 0; ni < 4; ni++)
        acc[mi][ni] = __builtin_amdgcn_mfma_f32_16x16x32_f16(af[mi], bf[ni], acc[mi][ni], 0, 0, 0);
  }

  // C/D layout (m89-verified): col = lane&15, row = (lane>>4)*4 + reg
  const int rb = kq * 4;
  if (MODE == 2) {
#pragma unroll
    for (int mi = 0; mi < 4; mi++) {
#pragma unroll
      for (int r = 0; r < 4; r++) {
        int row = mBase + wm * 64 + mi * 16 + rb + r;
        float rs = 0.f;
#pragma unroll
        for (int ni = 0; ni < 4; ni++) {
          int col = nBase + wn * 64 + ni * 16 + lr;
          float e = __expf(acc[mi][ni][r] * SCALE);  // |s|<~6: no max needed
          rs += e;
          outH[(size_t)row * Ncols + col] = (h16)e;
        }
        rs += __shfl_xor(rs, 1); rs += __shfl_xor(rs, 2);
        rs += __shfl_xor(rs, 4); rs += __shfl_xor(rs, 8);
        if (lr == 0) atomicAdd(&rowsum[row], rs);
      }
    }
  } else if (MODE == 3) {
#pragma unroll
    for (int mi = 0; mi < 4; mi++) {
#pragma unroll
      for (int r = 0; r < 4; r++) {
        int row = mBase + wm * 64 + mi * 16 + rb + r;
        float inv = 1.0f / rowsum[row];
#pragma unroll
        for (int ni = 0; ni < 4; ni++) {
          int col = nBase + wn * 64 + ni * 16 + lr;
          outF[(size_t)row * Ncols + col] = acc[mi][ni][r] * inv;
        }
      }
    }
  } else {
#pragma unroll
    for (int mi = 0; mi < 4; mi++) {
#pragma unroll
      for (int ni = 0; ni < 4; ni++) {
        int row0 = mBase + wm * 64 + mi * 16 + rb;
        int col = nBase + wn * 64 + ni * 16 + lr;
        if (MODE == 1 && col >= C_) {
          // V half: write transposed (B,C,E) as one packed 8B store
          float bv = bias[col];
          h16x4 pk;
#pragma unroll
          for (int r = 0; r < 4; r++) pk[r] = (h16)(acc[mi][ni][r] + bv);
          int zb = row0 >> 10, e = row0 & 1023;
          *(h16x4*)&outVt[((size_t)zb * C_ + (col - C_)) * E_ + e] = pk;
        } else {
#pragma unroll
          for (int r = 0; r < 4; r++) {
            int row = row0 + r;
            float v = acc[mi][ni][r] + bias[col];
            if (MODE == 0) outH[(size_t)row * Ncols + col] = (h16)v;
            else           outK[(size_t)row * C_ + col] = (h16)v;
          }
        }
      }
    }
  }
}

extern "C" void kernel_launch(void* const* d_in, const int* in_sizes, int n_in,
                              void* d_out, int out_size, void* d_ws, size_t ws_size,
                              hipStream_t stream) {
  const float* node  = (const float*)d_in[0];
  const float* hyper = (const float*)d_in[1];
  const float* Wq    = (const float*)d_in[2];
  const float* bq    = (const float*)d_in[3];
  const float* Wkv   = (const float*)d_in[4];
  const float* bkv   = (const float*)d_in[5];
  float* out = (float*)d_out;
  char* ws = (char*)d_ws;

  // node_h/hyper_h are dead once Q/KV are computed; S_h overlays them.
  h16* node_h  = (h16*)(ws + 0);           // 33554432
  h16* hyper_h = (h16*)(ws + 33554432);    //  8388608 (region0 ends 41943040)
  h16* S_h     = (h16*)(ws + 0);           // 67108864 (overlays region 0)
  h16* Q_h     = (h16*)(ws + 67108864);    // 33554432
  h16* K_h     = (h16*)(ws + 100663296);   //  8388608
  h16* Vt_h    = (h16*)(ws + 109051904);   //  8388608
  h16* Wq_h    = (h16*)(ws + 117440512);   //   524288
  h16* Wkv_h   = (h16*)(ws + 117964800);   //  1048576
  float* rowsum = (float*)(ws + 119013376);//   131072  total 119144448 B
  if (ws_size < 119144448u) return;

  cvt_kernel<<<dim3((B_ * N_ * C_ / 8 + 255) / 256), 256, 0, stream>>>(node, node_h, B_ * N_ * C_ / 8);
  cvt_kernel<<<dim3((B_ * E_ * C_ / 8 + 255) / 256), 256, 0, stream>>>(hyper, hyper_h, B_ * E_ * C_ / 8);
  cvt_kernel<<<dim3((C_ * C_ / 8 + 255) / 256), 256, 0, stream>>>(Wq, Wq_h, C_ * C_ / 8);
  cvt_kernel<<<dim3((2 * C_ * C_ / 8 + 255) / 256), 256, 0, stream>>>(Wkv, Wkv_h, 2 * C_ * C_ / 8);
  hipMemsetAsync(rowsum, 0, (size_t)B_ * N_ * sizeof(float), stream);

  // Q = node @ Wq^T + bq          (M=32768, N=512, K=512)
  gemm_bt<0><<<dim3(B_ * N_ / 128, C_ / 128), 256, 0, stream>>>(
      node_h, Wq_h, bq, Q_h, nullptr, nullptr, nullptr, nullptr, C_, C_);
  // KV = hyper @ Wkv^T + bkv      (M=8192, N=1024, K=512) -> K_h, Vt_h
  gemm_bt<1><<<dim3(B_ * E_ / 128, 2 * C_ / 128), 256, 0, stream>>>(
      hyper_h, Wkv_h, bkv, nullptr, K_h, Vt_h, nullptr, nullptr, 2 * C_, C_);
  // S' = exp(scale * Q @ K^T), rowsum += (per batch: M=4096, N=1024, K=512)
  gemm_bt<2><<<dim3(N_ / 128, E_ / 128, B_), 256, 0, stream>>>(
      Q_h, K_h, nullptr, S_h, nullptr, nullptr, nullptr, rowsum, E_, C_);
  // O = (S' @ V) / rowsum         (per batch: M=4096, N=512, K=1024), fp32 out
  gemm_bt<3><<<dim3(N_ / 128, C_ / 128, B_), 256, 0, stream>>>(
      S_h, Vt_h, nullptr, nullptr, nullptr, nullptr, out, rowsum, C_, E_);
}